// Round 15
// baseline (146.218 us; speedup 1.0000x reference)
//
#include <hip/hip_runtime.h>
#include <hip/hip_bf16.h>

// B=2048, T=128, I=130, H=10, 3H=30, D1=20
// Round-15: in-kernel scout prefetch. r14's probe experiment decoded:
//   - pure-read ceiling ~3.1 TB/s (m13's 6.29 "copy" = read+write summed)
//   - warmed xi_gemm = 88us = 273MB/3.1TB/s -> AT the read roofline
//   - unwarmed (110us) has ~20us latency-exposure that pre-touch closes
// So: each wave issues 7 fire-and-forget scalar loads (1 per 128-B line,
// 8KB stride) covering its own tiles 2-7, before the gll pipeline. They
// retire in vmcnt order before the glls (counting unchanged: 9/17/8),
// kept live by an asm sink AFTER the loop (no stall), sched_barrier(0)
// pins issue order. Probe kernel removed. Rest identical to r13.

#define BB 2048
#define TT 128
#define II 130
#define ROWS_PER_GRU (BB * TT)          // 262144
#define ROWS_TOTAL   (2 * ROWS_PER_GRU) // 524288
#define XI_BYTES ((size_t)ROWS_TOTAL * 30 * sizeof(float))   // 62,914,560
#define FRAG_U4_PER_GRU 1024            // 2t * 4q * 2p * 64 lanes

typedef __attribute__((ext_vector_type(8))) short short8v;  // 8 bf16
typedef __attribute__((ext_vector_type(4))) float f32x4;

union U8 { unsigned u[4]; short8v v; };
union SU { uint4 u; short8v v; };

__device__ __forceinline__ float sigmoidf_fast(float x) {
    return __fdividef(1.f, 1.f + __expf(-x));
}
__device__ __forceinline__ float tanhf_fast(float x) {
    float ax = fabsf(x);
    float e = __expf(-2.f * ax);
    float t = __fdividef(1.f - e, 1.f + e);
    return copysignf(t, x);
}

// truncation split of 2 fp32 -> packed bf16-hi pair + bf16-lo pair
__device__ __forceinline__ void split2(float x0, float x1,
                                       unsigned& hi, unsigned& lo) {
    unsigned u0 = __float_as_uint(x0), u1 = __float_as_uint(x1);
    hi = (u0 >> 16) | (u1 & 0xffff0000u);
    float f0 = __uint_as_float(u0 & 0xffff0000u);
    float f1 = __uint_as_float(u1 & 0xffff0000u);
    unsigned l0 = __float_as_uint(x0 - f0);
    unsigned l1 = __float_as_uint(x1 - f1);
    lo = (l0 >> 16) | (l1 & 0xffff0000u);
}

__device__ __forceinline__ void load_split(const float* __restrict__ p,
                                           short8v& hi, short8v& lo) {
    U8 H, L;
    #pragma unroll
    for (int i = 0; i < 4; ++i) {
        const float2 xy = *(const float2*)(p + 2 * i);
        split2(xy.x, xy.y, H.u[i], L.u[i]);
    }
    hi = H.v; lo = L.v;
}

__device__ __forceinline__ void split4(const float2* a,
                                       short8v& hi, short8v& lo) {
    U8 H, L;
    #pragma unroll
    for (int i = 0; i < 4; ++i) split2(a[i].x, a[i].y, H.u[i], L.u[i]);
    hi = H.v; lo = L.v;
}

// ---------------- prep_w: B fragments, once ----------------
__global__ void prep_w(const float* __restrict__ ruWih,
                       const float* __restrict__ enWih,
                       uint4* __restrict__ frags)
{
    const int tid  = threadIdx.x;      // 128 threads = 2 waves
    const int gru  = tid >> 6;
    const int lane = tid & 63;
    const int lr   = lane & 15;
    const int lk   = lane >> 4;
    const float* __restrict__ Wf = gru ? enWih : ruWih;
    uint4* __restrict__ fb = frags + gru * FRAG_U4_PER_GRU;
    #pragma unroll
    for (int t = 0; t < 2; ++t) {
        const int g  = 16 * t + lr;
        const int gv = (g < 30) ? g : 0;
        #pragma unroll
        for (int q = 0; q < 4; ++q) {
            short8v hi, lo;
            load_split(Wf + (long)gv * II + 32 * q + 8 * lk, hi, lo);
            if (g >= 30) {                 // mask cols 30,31
                const short8v z = {0,0,0,0,0,0,0,0};
                hi = z; lo = z;
            }
            SU sh, sl; sh.v = hi; sl.v = lo;
            fb[((t * 4 + q) * 2 + 0) * 64 + lane] = sh.u;
            fb[((t * 4 + q) * 2 + 1) * 64 + lane] = sl.u;
        }
    }
}

// ---------------- Phase 1: counted-vmcnt MFMA pipeline + scouts ----------------
#define MFMA16(A, B, C) __builtin_amdgcn_mfma_f32_16x16x32_bf16((A), (B), (C), 0, 0, 0)

#define VMWAIT_(N) asm volatile("s_waitcnt vmcnt(" #N ")" ::: "memory")
#define VMWAIT(N) do { VMWAIT_(N); __builtin_amdgcn_sched_barrier(0); } while (0)
#define LGKMWAIT0 do { asm volatile("s_waitcnt lgkmcnt(0)" ::: "memory"); \
                       __builtin_amdgcn_sched_barrier(0); } while (0)

// 9 global_load_lds issues: one 16x130-f32 tile -> linear LDS buffer.
__device__ __forceinline__ void issue_tile(const float4* __restrict__ s,
                                           float4* d, int lane) {
    #pragma unroll
    for (int c = 0; c < 8; ++c)
        __builtin_amdgcn_global_load_lds(
            (const __attribute__((address_space(1))) unsigned*)(s + 64 * c + lane),
            (__attribute__((address_space(3))) unsigned*)(d + 64 * c), 16, 0, 0);
    if (lane < 8)
        __builtin_amdgcn_global_load_lds(
            (const __attribute__((address_space(1))) unsigned*)(s + 512 + lane),
            (__attribute__((address_space(3))) unsigned*)(d + 512), 16, 0, 0);
}

__global__ __launch_bounds__(128)
void xi_gemm(const float* __restrict__ ru, const float* __restrict__ en,
             const float* __restrict__ ruWih, const float* __restrict__ rubih,
             const float* __restrict__ enWih, const float* __restrict__ enbih,
             const uint4* __restrict__ frags, float* __restrict__ xi)
{
    const int tid  = threadIdx.x;
    const int wv   = tid >> 6;           // 2 waves/block
    const int lane = tid & 63;
    const int lr   = lane & 15;          // A-row slot / C-col
    const int lk   = lane >> 4;          // k-subblock / C-row group
    const int w    = blockIdx.x * 2 + wv;            // wave 0..4095
    const int gru  = (w >= 2048);
    const long row0 = (long)(w & 2047) * 128;        // 8 tiles x 16 rows

    const float* __restrict__ X   = gru ? en    : ru;
    const float* __restrict__ Wf  = gru ? enWih : ruWih;
    const float* __restrict__ bih = gru ? enbih : rubih;

    // ---- prologue loads: B frags + bias + tail wts ----
    const uint4* __restrict__ fb = frags + gru * FRAG_U4_PER_GRU;
    short8v Bhi[2][4], Blo[2][4];
    #pragma unroll
    for (int t = 0; t < 2; ++t)
        #pragma unroll
        for (int q = 0; q < 4; ++q) {
            SU sh, sl;
            sh.u = fb[((t * 4 + q) * 2 + 0) * 64 + lane];
            sl.u = fb[((t * 4 + q) * 2 + 1) * 64 + lane];
            Bhi[t][q] = sh.v; Blo[t][q] = sl.v;
        }
    const int gv1 = (16 + lr < 30) ? 16 + lr : 0;
    const float bias0 = bih[lr];
    const float bias1 = bih[gv1];
    const float2 w0 = *(const float2*)(Wf + (long)lr  * II + 128);
    const float2 w1 = *(const float2*)(Wf + (long)gv1 * II + 128);

    // ---- double-buffered per-wave LDS (linear, zero-conflict per r7) ----
    __shared__ __align__(16) float ldsbuf[2][2][16 * II];  // 33,280 B/block
    float4* Bu[2] = { (float4*)ldsbuf[wv][0], (float4*)ldsbuf[wv][1] };

    const float4* __restrict__ src = (const float4*)(X + row0 * II);
    const long gb = (long)gru * ROWS_PER_GRU;

    // ---- SCOUT PREFETCH: 7 fire-and-forget loads, 1 per 128-B line,
    // covering this wave's tiles 2-7 (floats [4160, 16640)). Retire in
    // vmcnt order before the glls; kept live by the sink after the loop.
    float s0, s1, s2, s3, s4, s5, s6;
    {
        const float* __restrict__ sf = (const float*)src;
        const long lbase = 4160 + 32L * lane;
        long i0 = lbase;               if (i0 > 16639) i0 = 16639;
        long i1 = lbase + 2048;        if (i1 > 16639) i1 = 16639;
        long i2 = lbase + 4096;        if (i2 > 16639) i2 = 16639;
        long i3 = lbase + 6144;        if (i3 > 16639) i3 = 16639;
        long i4 = lbase + 8192;        if (i4 > 16639) i4 = 16639;
        long i5 = lbase + 10240;       if (i5 > 16639) i5 = 16639;
        long i6 = lbase + 12288;       if (i6 > 16639) i6 = 16639;
        s0 = sf[i0]; s1 = sf[i1]; s2 = sf[i2]; s3 = sf[i3];
        s4 = sf[i4]; s5 = sf[i5]; s6 = sf[i6];
    }
    __builtin_amdgcn_sched_barrier(0);   // pin scout issue before glls

    issue_tile(src, Bu[0], lane);               // gll tile 0 (9 ops)
    issue_tile(src + 520, Bu[1], lane);         // gll tile 1 (9 ops)

    #pragma unroll
    for (int t = 0; t < 8; ++t) {
        // counted wait: tile t's 9 loads complete; keep the rest in flight
        // (7 scouts are oldest and retire first; counts unchanged from r13)
        if (t == 0)      VMWAIT(9);
        else if (t == 7) VMWAIT(8);
        else             VMWAIT(17);            // 9 loads + 8 stores in flight

        const float* __restrict__ buf = (const float*)ldsbuf[wv][t & 1];

        // ds_reads for the whole tile into registers
        float2 A[4][4];
        #pragma unroll
        for (int q = 0; q < 4; ++q) {
            const float* __restrict__ ap = buf + lr * II + 32 * q + 8 * lk;
            #pragma unroll
            for (int j = 0; j < 4; ++j) A[q][j] = *(const float2*)(ap + 2 * j);
        }
        float2 tl[4];
        #pragma unroll
        for (int r = 0; r < 4; ++r)
            tl[r] = *(const float2*)(buf + (4 * lk + r) * II + 128);

        LGKMWAIT0;                               // reads done before overwrite

        if (t + 2 < 8)                           // refill just-consumed buffer
            issue_tile(src + 520 * (t + 2), Bu[t & 1], lane);

        // ---- compute: 24 MFMA, 3-term bf16 emulation (verified r6-r14) ----
        f32x4 a0 = (f32x4){bias0, bias0, bias0, bias0};
        f32x4 a1 = (f32x4){bias1, bias1, bias1, bias1};
        #pragma unroll
        for (int q = 0; q < 4; ++q) {
            short8v ahi, alo;
            split4(A[q], ahi, alo);
            a0 = MFMA16(ahi, Bhi[0][q], a0);
            a0 = MFMA16(ahi, Blo[0][q], a0);
            a0 = MFMA16(alo, Bhi[0][q], a0);
            a1 = MFMA16(ahi, Bhi[1][q], a1);
            a1 = MFMA16(ahi, Blo[1][q], a1);
            a1 = MFMA16(alo, Bhi[1][q], a1);
        }

        // ---- k-tail + store. C: col=lr, row-in-tile=4*lk+r ----
        #pragma unroll
        for (int r = 0; r < 4; ++r) {
            const long rr = row0 + 16 * t + 4 * lk + r;
            float* __restrict__ xo = xi + (gb + rr) * 30;
            xo[lr] = a0[r] + tl[r].x * w0.x + tl[r].y * w0.y;
            if (lr < 14)
                xo[16 + lr] = a1[r] + tl[r].x * w1.x + tl[r].y * w1.y;
        }
    }

    // keep the scout loads alive (never stalls: they retired long ago)
    asm volatile("" :: "v"(s0), "v"(s1), "v"(s2), "v"(s3),
                       "v"(s4), "v"(s5), "v"(s6));
}

// ---------------- Phase 2: recurrent scan (r7 version) ----------------
__global__ __launch_bounds__(256, 4)
void gru_scan(const float* __restrict__ xi,
              const float* __restrict__ ruWhh, const float* __restrict__ rubhh,
              const float* __restrict__ enWhh, const float* __restrict__ enbhh,
              const float* __restrict__ W1, const float* __restrict__ b1,
              const float* __restrict__ W2, const float* __restrict__ b2,
              float* __restrict__ out)
{
    const int tid  = threadIdx.x;
    const int wv   = tid >> 6;
    const int lane = tid & 63;
    const int c    = lane >> 5;
    const int k    = lane & 31;
    const int kq   = (k < 10) ? k : 0;
    const int chain = (blockIdx.x * 4 + wv) * 2 + c;
    const int gru   = chain >> 11;
    const int b     = chain & (BB - 1);

    const float* __restrict__ Whh = gru ? enWhh : ruWhh;
    const float* __restrict__ bhh = gru ? enbhh : rubhh;

    float whhR[10], whhZ[10], whhN[10];
    #pragma unroll
    for (int j = 0; j < 10; ++j) {
        whhR[j] = Whh[kq * 10 + j];
        whhZ[j] = Whh[(10 + kq) * 10 + j];
        whhN[j] = Whh[(20 + kq) * 10 + j];
    }
    const float bR = bhh[kq], bZ = bhh[10 + kq], bN = bhh[20 + kq];

    __shared__ __align__(16) float lds[4][32];
    float* __restrict__ H = lds[wv] + c * 16;
    if (k < 12) H[k] = 0.f;
    float hown = 0.f;

    const float* __restrict__ xrow =
        xi + ((long)gru * ROWS_PER_GRU + (long)b * TT) * 30;

    float xR0 = xrow[kq],      xZ0 = xrow[10 + kq],  xN0 = xrow[20 + kq];
    float xR1 = xrow[30 + kq], xZ1 = xrow[40 + kq],  xN1 = xrow[50 + kq];

    for (int t = 0; t < TT; ++t) {
        const float xR = xR0, xZ = xZ0, xN = xN0;
        xR0 = xR1; xZ0 = xZ1; xN0 = xN1;
        {
            const int tn = (t + 2 < TT) ? t + 2 : TT - 1;
            const float* __restrict__ xp = xrow + (long)tn * 30;
            xR1 = xp[kq]; xZ1 = xp[10 + kq]; xN1 = xp[20 + kq];
        }

        const float4 h03 = *(const float4*)(H);
        const float4 h47 = *(const float4*)(H + 4);
        const float2 h89 = *(const float2*)(H + 8);

        float gr = bR, gz = bZ, gn = bN;
        gr = fmaf(whhR[0], h03.x, gr); gz = fmaf(whhZ[0], h03.x, gz); gn = fmaf(whhN[0], h03.x, gn);
        gr = fmaf(whhR[1], h03.y, gr); gz = fmaf(whhZ[1], h03.y, gz); gn = fmaf(whhN[1], h03.y, gn);
        gr = fmaf(whhR[2], h03.z, gr); gz = fmaf(whhZ[2], h03.z, gz); gn = fmaf(whhN[2], h03.z, gn);
        gr = fmaf(whhR[3], h03.w, gr); gz = fmaf(whhZ[3], h03.w, gz); gn = fmaf(whhN[3], h03.w, gn);
        gr = fmaf(whhR[4], h47.x, gr); gz = fmaf(whhZ[4], h47.x, gz); gn = fmaf(whhN[4], h47.x, gn);
        gr = fmaf(whhR[5], h47.y, gr); gz = fmaf(whhZ[5], h47.y, gz); gn = fmaf(whhN[5], h47.y, gn);
        gr = fmaf(whhR[6], h47.z, gr); gz = fmaf(whhZ[6], h47.z, gz); gn = fmaf(whhN[6], h47.z, gn);
        gr = fmaf(whhR[7], h47.w, gr); gz = fmaf(whhZ[7], h47.w, gz); gn = fmaf(whhN[7], h47.w, gn);
        gr = fmaf(whhR[8], h89.x, gr); gz = fmaf(whhZ[8], h89.x, gz); gn = fmaf(whhN[8], h89.x, gn);
        gr = fmaf(whhR[9], h89.y, gr); gz = fmaf(whhZ[9], h89.y, gz); gn = fmaf(whhN[9], h89.y, gn);

        const float r = sigmoidf_fast(xR + gr);
        const float z = sigmoidf_fast(xZ + gz);
        const float n = tanhf_fast(xN + r * gn);
        hown = fmaf(z, hown - n, n);
        if (k < 10) H[k] = hown;
    }

    float val = 0.f;
    if (k < 10) {
        float v = 0.f;
        #pragma unroll
        for (int d = 0; d < 20; ++d)
            v = fmaf(W2[d], W1[d * 20 + gru * 10 + k], v);
        val = v * hown;
        if (k == 0 && gru == 0) {
            float c0 = b2[0];
            #pragma unroll
            for (int d = 0; d < 20; ++d) c0 = fmaf(W2[d], b1[d], c0);
            val += c0;
        }
    }
    val += __shfl_xor(val, 8);
    val += __shfl_xor(val, 4);
    val += __shfl_xor(val, 2);
    val += __shfl_xor(val, 1);
    if (k == 0) atomicAdd(&out[b], val);
}

// ---------------- Fallback: monolithic kernel ----------------
__global__ __launch_bounds__(256, 4)
void gru_fused(const float* __restrict__ ru, const float* __restrict__ en,
               const float* __restrict__ ruWih, const float* __restrict__ ruWhh,
               const float* __restrict__ rubih, const float* __restrict__ rubhh,
               const float* __restrict__ enWih, const float* __restrict__ enWhh,
               const float* __restrict__ enbih, const float* __restrict__ enbhh,
               const float* __restrict__ W1, const float* __restrict__ b1,
               const float* __restrict__ W2, const float* __restrict__ b2,
               float* __restrict__ out)
{
    const int tid  = threadIdx.x;
    const int wv   = tid >> 6;
    const int lane = tid & 63;
    const int g    = lane & 31;
    const int h    = lane >> 5;
    const int wid  = blockIdx.x * 4 + wv;
    const int gru  = wid >> 11;
    const int b    = wid & (BB - 1);

    const float* __restrict__ x   = gru ? en    : ru;
    const float* __restrict__ Wih = gru ? enWih : ruWih;
    const float* __restrict__ Whh = gru ? enWhh : ruWhh;
    const float* __restrict__ bih = gru ? enbih : rubih;
    const float* __restrict__ bhh = gru ? enbhh : rubhh;

    __shared__ __align__(16) float lds[4][176];
    float* __restrict__ X    = lds[wv];
    float* __restrict__ PRE  = X + 132;
    float* __restrict__ Hbuf = X + 164;

    const int gq = (g < 30) ? g : 0;
    float wih[64];
    #pragma unroll
    for (int j = 0; j < 64; ++j) wih[j] = Wih[gq * II + h * 64 + j];
    const float w_e = Wih[gq * II + 128 + h];
    float whh[10];
    #pragma unroll
    for (int k = 0; k < 10; ++k) whh[k] = Whh[gq * 10 + k];
    const float bihg = bih[gq];
    const float bhhg = bhh[gq];

    if (lane < 12) Hbuf[lane] = 0.f;
    float hown = 0.f;

    const float* __restrict__ xrow = x + (size_t)b * (TT * II);
    float xa = xrow[lane];
    float xb = xrow[64 + lane];
    float xc = (lane < 2) ? xrow[128 + lane] : 0.f;

    for (int t = 0; t < TT; ++t) {
        X[lane] = xa;
        X[64 + lane] = xb;
        if (lane < 2) X[128 + lane] = xc;
        {
            const int tn = (t < TT - 1) ? t + 1 : t;
            const float* __restrict__ xn = xrow + (size_t)tn * II;
            xa = xn[lane];
            xb = xn[64 + lane];
            xc = (lane < 2) ? xn[128 + lane] : 0.f;
        }
        const float4 h03 = *(const float4*)(Hbuf);
        const float4 h47 = *(const float4*)(Hbuf + 4);
        const float2 h89 = *(const float2*)(Hbuf + 8);
        float gh0 = fmaf(whh[0], h03.x, bhhg);
        float gh1 = whh[1] * h03.y;
        gh0 = fmaf(whh[2], h03.z, gh0);
        gh1 = fmaf(whh[3], h03.w, gh1);
        gh0 = fmaf(whh[4], h47.x, gh0);
        gh1 = fmaf(whh[5], h47.y, gh1);
        gh0 = fmaf(whh[6], h47.z, gh0);
        gh1 = fmaf(whh[7], h47.w, gh1);
        gh0 = fmaf(whh[8], h89.x, gh0);
        gh1 = fmaf(whh[9], h89.y, gh1);
        const float gh = gh0 + gh1;

        float s0 = 0.f, s1 = 0.f, s2 = 0.f, s3 = 0.f;
        const float4* __restrict__ xb4 = (const float4*)(X + h * 64);
        #pragma unroll
        for (int c = 0; c < 16; ++c) {
            const float4 v = xb4[c];
            s0 = fmaf(wih[4 * c + 0], v.x, s0);
            s1 = fmaf(wih[4 * c + 1], v.y, s1);
            s2 = fmaf(wih[4 * c + 2], v.z, s2);
            s3 = fmaf(wih[4 * c + 3], v.w, s3);
        }
        float s = (s0 + s1) + (s2 + s3);
        s = fmaf(w_e, X[128 + h], s);
        s += __shfl_xor(s, 32);

        const float xiv = s + bihg;
        const float pre = xiv + gh;
        if (lane < 30) PRE[lane] = pre;
        const float rpre = PRE[(g - 20) & 31];
        const float zpre = PRE[(g - 10) & 31];
        const float r = sigmoidf_fast(rpre);
        const float z = sigmoidf_fast(zpre);
        const float n = tanhf_fast(xiv + r * gh);
        const float hnew = (1.f - z) * n + z * hown;
        hown = hnew;
        if (lane >= 20 && lane < 30) Hbuf[lane - 20] = hnew;
    }

    float val = 0.f;
    if (lane < 10) {
        const float hk = Hbuf[lane];
        float v = 0.f;
        #pragma unroll
        for (int d = 0; d < 20; ++d)
            v = fmaf(W2[d], W1[d * 20 + gru * 10 + lane], v);
        val = v * hk;
        if (lane == 0 && gru == 0) {
            float c0 = b2[0];
            #pragma unroll
            for (int d = 0; d < 20; ++d) c0 = fmaf(W2[d], b1[d], c0);
            val += c0;
        }
    }
    #pragma unroll
    for (int o = 32; o > 0; o >>= 1) val += __shfl_xor(val, o);
    if (lane == 0) atomicAdd(&out[b], val);
}

extern "C" void kernel_launch(void* const* d_in, const int* in_sizes, int n_in,
                              void* d_out, int out_size, void* d_ws, size_t ws_size,
                              hipStream_t stream) {
    (void)in_sizes; (void)n_in;
    const float* ru    = (const float*)d_in[0];
    const float* en    = (const float*)d_in[1];
    const float* ruWih = (const float*)d_in[2];
    const float* ruWhh = (const float*)d_in[3];
    const float* rubih = (const float*)d_in[4];
    const float* rubhh = (const float*)d_in[5];
    const float* enWih = (const float*)d_in[6];
    const float* enWhh = (const float*)d_in[7];
    const float* enbih = (const float*)d_in[8];
    const float* enbhh = (const float*)d_in[9];
    const float* W1    = (const float*)d_in[10];
    const float* b1    = (const float*)d_in[11];
    const float* W2    = (const float*)d_in[12];
    const float* b2    = (const float*)d_in[13];
    float* out = (float*)d_out;

    hipMemsetAsync(d_out, 0, (size_t)out_size * sizeof(float), stream);

    const size_t frag_bytes = 2 * FRAG_U4_PER_GRU * sizeof(uint4);  // 32 KB
    if (ws_size >= XI_BYTES + frag_bytes) {
        float* xi = (float*)d_ws;
        uint4* frags = (uint4*)((char*)d_ws + XI_BYTES);
        prep_w<<<dim3(1), dim3(128), 0, stream>>>(ruWih, enWih, frags);
        xi_gemm<<<dim3(2048), dim3(128), 0, stream>>>(
            ru, en, ruWih, rubih, enWih, enbih, frags, xi);
        gru_scan<<<dim3(512), dim3(256), 0, stream>>>(
            xi, ruWhh, rubhh, enWhh, enbhh, W1, b1, W2, b2, out);
    } else {
        gru_fused<<<dim3(1024), dim3(256), 0, stream>>>(
            ru, en, ruWih, ruWhh, rubih, rubhh,
            enWih, enWhh, enbih, enbhh, W1, b1, W2, b2, out);
    }
}

// Round 16
// 118.961 us; speedup vs baseline: 1.2291x; 1.2291x over previous
//
#include <hip/hip_runtime.h>
#include <hip/hip_bf16.h>

// B=2048, T=128, I=130, H=10, 3H=30, D1=20
// Round-16: RESTORE round-7 optimum (118.6us total, best of 15 rounds).
// r15's scout prefetch refuted: +100MB HBM double-fetch (L2 eviction before
// use), +20us. r14 decoded the platform: pure-read ceiling ~3.0-3.1 TB/s
// (m13's 6.29 is copy = read+write); xi_gemm at 104us delivers 273MB at
// ~2.6 TB/s -> within ~15% of the read roofline; all-pipes-idle is the
// EXPECTED signature there, not a symptom. Fancier variants (gll+counted
// vmcnt r13, prep_w r9/r10, no-LDS r9, scouts r15) were all equal or worse
// in total. This file = round-7 kernel verbatim.
//   xi_gemm: 8192 waves x 4 serial tiles x 16 rows; 9 coalesced float4
//            register-prefetch loads/tile -> per-wave linear LDS (zero
//            conflicts); 24 MFMA bf16 hi/lo 3-term (absmax 1.95e-3).
//   gru_scan: 2 chains/wave, lane-owned gates, LDS h-roundtrip, 2-deep
//            prefetch of L3-hot xi (14us, 4.4 TB/s effective).
// Fallback: monolithic kernel if ws_size < 63 MB.

#define BB 2048
#define TT 128
#define II 130
#define ROWS_PER_GRU (BB * TT)          // 262144
#define ROWS_TOTAL   (2 * ROWS_PER_GRU) // 524288

typedef __attribute__((ext_vector_type(8))) short short8v;  // 8 bf16
typedef __attribute__((ext_vector_type(4))) float f32x4;

__device__ __forceinline__ float sigmoidf_fast(float x) {
    return __fdividef(1.f, 1.f + __expf(-x));
}
__device__ __forceinline__ float tanhf_fast(float x) {
    float ax = fabsf(x);
    float e = __expf(-2.f * ax);
    float t = __fdividef(1.f - e, 1.f + e);
    return copysignf(t, x);
}

// truncation split of 2 fp32 -> packed bf16-hi pair + bf16-lo pair
__device__ __forceinline__ void split2(float x0, float x1,
                                       unsigned& hi, unsigned& lo) {
    unsigned u0 = __float_as_uint(x0), u1 = __float_as_uint(x1);
    hi = (u0 >> 16) | (u1 & 0xffff0000u);
    float f0 = __uint_as_float(u0 & 0xffff0000u);
    float f1 = __uint_as_float(u1 & 0xffff0000u);
    unsigned l0 = __float_as_uint(x0 - f0);
    unsigned l1 = __float_as_uint(x1 - f1);
    lo = (l0 >> 16) | (l1 & 0xffff0000u);
}

union U8 { unsigned u[4]; short8v v; };

// split 8 consecutive fp32 (8B-aligned, any addrspace) into bf16x8 hi/lo
__device__ __forceinline__ void load_split(const float* __restrict__ p,
                                           short8v& hi, short8v& lo) {
    U8 H, L;
    #pragma unroll
    for (int i = 0; i < 4; ++i) {
        const float2 xy = *(const float2*)(p + 2 * i);
        split2(xy.x, xy.y, H.u[i], L.u[i]);
    }
    hi = H.v; lo = L.v;
}

// ---------------- Phase 1: input projection via MFMA ----------------
__global__ __launch_bounds__(256)
void xi_gemm(const float* __restrict__ ru, const float* __restrict__ en,
             const float* __restrict__ ruWih, const float* __restrict__ rubih,
             const float* __restrict__ enWih, const float* __restrict__ enbih,
             float* __restrict__ xi)
{
    const int tid  = threadIdx.x;
    const int wv   = tid >> 6;
    const int lane = tid & 63;
    const int lr   = lane & 15;          // A-row / B-col / C-col slot
    const int lk   = lane >> 4;          // k-subblock (0..3)
    const int w    = blockIdx.x * 4 + wv;           // wave 0..8191
    const int gru  = (w >= 4096);
    const long row0 = (long)(w & 4095) * 64;        // local row in this gru

    const float* __restrict__ X   = gru ? en    : ru;
    const float* __restrict__ Wf  = gru ? enWih : ruWih;
    const float* __restrict__ bih = gru ? enbih : rubih;

    // ---- B fragments (weights), hi/lo, 2 n-tiles x 4 k-blocks ----
    short8v Bhi[2][4], Blo[2][4];
    float biasv[2], wt0[2], wt1[2];
    #pragma unroll
    for (int t = 0; t < 2; ++t) {
        const int g = 16 * t + lr;
        const int gv = (g < 30) ? g : 0;
        #pragma unroll
        for (int q = 0; q < 4; ++q)
            load_split(Wf + (long)gv * II + 32 * q + 8 * lk, Bhi[t][q], Blo[t][q]);
        if (g >= 30) {                    // mask cols 30,31
            const short8v z = {0, 0, 0, 0, 0, 0, 0, 0};
            #pragma unroll
            for (int q = 0; q < 4; ++q) { Bhi[t][q] = z; Blo[t][q] = z; }
        }
        biasv[t] = bih[gv];
        const float2 wt = *(const float2*)(Wf + (long)gv * II + 128);
        wt0[t] = wt.x; wt1[t] = wt.y;
    }

    // ---- per-wave LDS tile: 16 rows x 130 f32 = 520 float4 (8320 B) ----
    __shared__ __align__(16) float lds[4][16 * II];
    float4* __restrict__ L4 = (float4*)lds[wv];
    const float* __restrict__ Lf = lds[wv];

    // wave's 64-row block is one contiguous chunk of 2080 float4
    const float4* __restrict__ src = (const float4*)X + row0 * (II / 2) / 2;

    const long gb = (long)gru * ROWS_PER_GRU;

    // preload tile 0 (coalesced: 8 full wave-loads + 8-lane tail)
    float4 pf0, pf1, pf2, pf3, pf4, pf5, pf6, pf7, pft;
    {
        const float4* __restrict__ s = src;
        pf0 = s[lane];        pf1 = s[64 + lane];
        pf2 = s[128 + lane];  pf3 = s[192 + lane];
        pf4 = s[256 + lane];  pf5 = s[320 + lane];
        pf6 = s[384 + lane];  pf7 = s[448 + lane];
        if (lane < 8) pft = s[512 + lane];
    }

    #pragma unroll
    for (int t = 0; t < 4; ++t) {
        // stage tile t to LDS (in-wave DS ordering: prior reads done first)
        L4[lane]       = pf0;  L4[64 + lane]  = pf1;
        L4[128 + lane] = pf2;  L4[192 + lane] = pf3;
        L4[256 + lane] = pf4;  L4[320 + lane] = pf5;
        L4[384 + lane] = pf6;  L4[448 + lane] = pf7;
        if (lane < 8) L4[512 + lane] = pft;

        // prefetch tile t+1 (in flight during this tile's compute)
        if (t < 3) {
            const float4* __restrict__ s = src + 520 * (t + 1);
            pf0 = s[lane];        pf1 = s[64 + lane];
            pf2 = s[128 + lane];  pf3 = s[192 + lane];
            pf4 = s[256 + lane];  pf5 = s[320 + lane];
            pf6 = s[384 + lane];  pf7 = s[448 + lane];
            if (lane < 8) pft = s[512 + lane];
        }

        // ---- compute tile t: K=128 via 4 k-blocks, 3-term bf16 emulation ----
        f32x4 a0 = (f32x4){biasv[0], biasv[0], biasv[0], biasv[0]};
        f32x4 a1 = (f32x4){biasv[1], biasv[1], biasv[1], biasv[1]};
        #pragma unroll
        for (int q = 0; q < 4; ++q) {
            short8v ahi, alo;
            load_split(Lf + lr * II + 32 * q + 8 * lk, ahi, alo);
            a0 = __builtin_amdgcn_mfma_f32_16x16x32_bf16(ahi, Bhi[0][q], a0, 0, 0, 0);
            a0 = __builtin_amdgcn_mfma_f32_16x16x32_bf16(ahi, Blo[0][q], a0, 0, 0, 0);
            a0 = __builtin_amdgcn_mfma_f32_16x16x32_bf16(alo, Bhi[0][q], a0, 0, 0, 0);
            a1 = __builtin_amdgcn_mfma_f32_16x16x32_bf16(ahi, Bhi[1][q], a1, 0, 0, 0);
            a1 = __builtin_amdgcn_mfma_f32_16x16x32_bf16(ahi, Blo[1][q], a1, 0, 0, 0);
            a1 = __builtin_amdgcn_mfma_f32_16x16x32_bf16(alo, Bhi[1][q], a1, 0, 0, 0);
        }

        // ---- k-tail (cols 128,129 from LDS) + store ----
        // C layout: col = lr, row-in-tile = 4*lk + r (verified r6-r15)
        #pragma unroll
        for (int r = 0; r < 4; ++r) {
            const int rowin = 4 * lk + r;
            const float2 xt = *(const float2*)(Lf + rowin * II + 128);
            const long rr = row0 + 16 * t + rowin;
            float* __restrict__ xo = xi + (gb + rr) * 30;
            const float v0 = a0[r] + xt.x * wt0[0] + xt.y * wt1[0];
            xo[lr] = v0;                          // g = lr (0..15)
            if (lr < 14) {
                const float v1 = a1[r] + xt.x * wt0[1] + xt.y * wt1[1];
                xo[16 + lr] = v1;                 // g = 16+lr (16..29)
            }
        }
    }
}

// ---------------- Phase 2: recurrent scan ----------------
__global__ __launch_bounds__(256, 4)
void gru_scan(const float* __restrict__ xi,
              const float* __restrict__ ruWhh, const float* __restrict__ rubhh,
              const float* __restrict__ enWhh, const float* __restrict__ enbhh,
              const float* __restrict__ W1, const float* __restrict__ b1,
              const float* __restrict__ W2, const float* __restrict__ b2,
              float* __restrict__ out)
{
    const int tid  = threadIdx.x;
    const int wv   = tid >> 6;
    const int lane = tid & 63;
    const int c    = lane >> 5;
    const int k    = lane & 31;
    const int kq   = (k < 10) ? k : 0;
    const int chain = (blockIdx.x * 4 + wv) * 2 + c;
    const int gru   = chain >> 11;
    const int b     = chain & (BB - 1);

    const float* __restrict__ Whh = gru ? enWhh : ruWhh;
    const float* __restrict__ bhh = gru ? enbhh : rubhh;

    float whhR[10], whhZ[10], whhN[10];
    #pragma unroll
    for (int j = 0; j < 10; ++j) {
        whhR[j] = Whh[kq * 10 + j];
        whhZ[j] = Whh[(10 + kq) * 10 + j];
        whhN[j] = Whh[(20 + kq) * 10 + j];
    }
    const float bR = bhh[kq], bZ = bhh[10 + kq], bN = bhh[20 + kq];

    __shared__ __align__(16) float lds[4][32];
    float* __restrict__ H = lds[wv] + c * 16;
    if (k < 12) H[k] = 0.f;
    float hown = 0.f;

    const float* __restrict__ xrow =
        xi + ((long)gru * ROWS_PER_GRU + (long)b * TT) * 30;

    float xR0 = xrow[kq],      xZ0 = xrow[10 + kq],  xN0 = xrow[20 + kq];
    float xR1 = xrow[30 + kq], xZ1 = xrow[40 + kq],  xN1 = xrow[50 + kq];

    for (int t = 0; t < TT; ++t) {
        const float xR = xR0, xZ = xZ0, xN = xN0;
        xR0 = xR1; xZ0 = xZ1; xN0 = xN1;
        {
            const int tn = (t + 2 < TT) ? t + 2 : TT - 1;
            const float* __restrict__ xp = xrow + (long)tn * 30;
            xR1 = xp[kq]; xZ1 = xp[10 + kq]; xN1 = xp[20 + kq];
        }

        const float4 h03 = *(const float4*)(H);
        const float4 h47 = *(const float4*)(H + 4);
        const float2 h89 = *(const float2*)(H + 8);

        float gr = bR, gz = bZ, gn = bN;
        gr = fmaf(whhR[0], h03.x, gr); gz = fmaf(whhZ[0], h03.x, gz); gn = fmaf(whhN[0], h03.x, gn);
        gr = fmaf(whhR[1], h03.y, gr); gz = fmaf(whhZ[1], h03.y, gz); gn = fmaf(whhN[1], h03.y, gn);
        gr = fmaf(whhR[2], h03.z, gr); gz = fmaf(whhZ[2], h03.z, gz); gn = fmaf(whhN[2], h03.z, gn);
        gr = fmaf(whhR[3], h03.w, gr); gz = fmaf(whhZ[3], h03.w, gz); gn = fmaf(whhN[3], h03.w, gn);
        gr = fmaf(whhR[4], h47.x, gr); gz = fmaf(whhZ[4], h47.x, gz); gn = fmaf(whhN[4], h47.x, gn);
        gr = fmaf(whhR[5], h47.y, gr); gz = fmaf(whhZ[5], h47.y, gz); gn = fmaf(whhN[5], h47.y, gn);
        gr = fmaf(whhR[6], h47.z, gr); gz = fmaf(whhZ[6], h47.z, gz); gn = fmaf(whhN[6], h47.z, gn);
        gr = fmaf(whhR[7], h47.w, gr); gz = fmaf(whhZ[7], h47.w, gz); gn = fmaf(whhN[7], h47.w, gn);
        gr = fmaf(whhR[8], h89.x, gr); gz = fmaf(whhZ[8], h89.x, gz); gn = fmaf(whhN[8], h89.x, gn);
        gr = fmaf(whhR[9], h89.y, gr); gz = fmaf(whhZ[9], h89.y, gz); gn = fmaf(whhN[9], h89.y, gn);

        const float r = sigmoidf_fast(xR + gr);
        const float z = sigmoidf_fast(xZ + gz);
        const float n = tanhf_fast(xN + r * gn);
        hown = fmaf(z, hown - n, n);
        if (k < 10) H[k] = hown;
    }

    float val = 0.f;
    if (k < 10) {
        float v = 0.f;
        #pragma unroll
        for (int d = 0; d < 20; ++d)
            v = fmaf(W2[d], W1[d * 20 + gru * 10 + k], v);
        val = v * hown;
        if (k == 0 && gru == 0) {
            float c0 = b2[0];
            #pragma unroll
            for (int d = 0; d < 20; ++d) c0 = fmaf(W2[d], b1[d], c0);
            val += c0;
        }
    }
    val += __shfl_xor(val, 8);
    val += __shfl_xor(val, 4);
    val += __shfl_xor(val, 2);
    val += __shfl_xor(val, 1);
    if (k == 0) atomicAdd(&out[b], val);
}

// ---------------- Fallback: monolithic kernel ----------------
__global__ __launch_bounds__(256, 4)
void gru_fused(const float* __restrict__ ru, const float* __restrict__ en,
               const float* __restrict__ ruWih, const float* __restrict__ ruWhh,
               const float* __restrict__ rubih, const float* __restrict__ rubhh,
               const float* __restrict__ enWih, const float* __restrict__ enWhh,
               const float* __restrict__ enbih, const float* __restrict__ enbhh,
               const float* __restrict__ W1, const float* __restrict__ b1,
               const float* __restrict__ W2, const float* __restrict__ b2,
               float* __restrict__ out)
{
    const int tid  = threadIdx.x;
    const int wv   = tid >> 6;
    const int lane = tid & 63;
    const int g    = lane & 31;
    const int h    = lane >> 5;
    const int wid  = blockIdx.x * 4 + wv;
    const int gru  = wid >> 11;
    const int b    = wid & (BB - 1);

    const float* __restrict__ x   = gru ? en    : ru;
    const float* __restrict__ Wih = gru ? enWih : ruWih;
    const float* __restrict__ Whh = gru ? enWhh : ruWhh;
    const float* __restrict__ bih = gru ? enbih : rubih;
    const float* __restrict__ bhh = gru ? enbhh : rubhh;

    __shared__ __align__(16) float lds[4][176];
    float* __restrict__ X    = lds[wv];
    float* __restrict__ PRE  = X + 132;
    float* __restrict__ Hbuf = X + 164;

    const int gq = (g < 30) ? g : 0;
    float wih[64];
    #pragma unroll
    for (int j = 0; j < 64; ++j) wih[j] = Wih[gq * II + h * 64 + j];
    const float w_e = Wih[gq * II + 128 + h];
    float whh[10];
    #pragma unroll
    for (int k = 0; k < 10; ++k) whh[k] = Whh[gq * 10 + k];
    const float bihg = bih[gq];
    const float bhhg = bhh[gq];

    if (lane < 12) Hbuf[lane] = 0.f;
    float hown = 0.f;

    const float* __restrict__ xrow = x + (size_t)b * (TT * II);
    float xa = xrow[lane];
    float xb = xrow[64 + lane];
    float xc = (lane < 2) ? xrow[128 + lane] : 0.f;

    for (int t = 0; t < TT; ++t) {
        X[lane] = xa;
        X[64 + lane] = xb;
        if (lane < 2) X[128 + lane] = xc;
        {
            const int tn = (t < TT - 1) ? t + 1 : t;
            const float* __restrict__ xn = xrow + (size_t)tn * II;
            xa = xn[lane];
            xb = xn[64 + lane];
            xc = (lane < 2) ? xn[128 + lane] : 0.f;
        }
        const float4 h03 = *(const float4*)(Hbuf);
        const float4 h47 = *(const float4*)(Hbuf + 4);
        const float2 h89 = *(const float2*)(Hbuf + 8);
        float gh0 = fmaf(whh[0], h03.x, bhhg);
        float gh1 = whh[1] * h03.y;
        gh0 = fmaf(whh[2], h03.z, gh0);
        gh1 = fmaf(whh[3], h03.w, gh1);
        gh0 = fmaf(whh[4], h47.x, gh0);
        gh1 = fmaf(whh[5], h47.y, gh1);
        gh0 = fmaf(whh[6], h47.z, gh0);
        gh1 = fmaf(whh[7], h47.w, gh1);
        gh0 = fmaf(whh[8], h89.x, gh0);
        gh1 = fmaf(whh[9], h89.y, gh1);
        const float gh = gh0 + gh1;

        float s0 = 0.f, s1 = 0.f, s2 = 0.f, s3 = 0.f;
        const float4* __restrict__ xb4 = (const float4*)(X + h * 64);
        #pragma unroll
        for (int c = 0; c < 16; ++c) {
            const float4 v = xb4[c];
            s0 = fmaf(wih[4 * c + 0], v.x, s0);
            s1 = fmaf(wih[4 * c + 1], v.y, s1);
            s2 = fmaf(wih[4 * c + 2], v.z, s2);
            s3 = fmaf(wih[4 * c + 3], v.w, s3);
        }
        float s = (s0 + s1) + (s2 + s3);
        s = fmaf(w_e, X[128 + h], s);
        s += __shfl_xor(s, 32);

        const float xiv = s + bihg;
        const float pre = xiv + gh;
        if (lane < 30) PRE[lane] = pre;
        const float rpre = PRE[(g - 20) & 31];
        const float zpre = PRE[(g - 10) & 31];
        const float r = sigmoidf_fast(rpre);
        const float z = sigmoidf_fast(zpre);
        const float n = tanhf_fast(xiv + r * gh);
        const float hnew = (1.f - z) * n + z * hown;
        hown = hnew;
        if (lane >= 20 && lane < 30) Hbuf[lane - 20] = hnew;
    }

    float val = 0.f;
    if (lane < 10) {
        const float hk = Hbuf[lane];
        float v = 0.f;
        #pragma unroll
        for (int d = 0; d < 20; ++d)
            v = fmaf(W2[d], W1[d * 20 + gru * 10 + lane], v);
        val = v * hk;
        if (lane == 0 && gru == 0) {
            float c0 = b2[0];
            #pragma unroll
            for (int d = 0; d < 20; ++d) c0 = fmaf(W2[d], b1[d], c0);
            val += c0;
        }
    }
    #pragma unroll
    for (int o = 32; o > 0; o >>= 1) val += __shfl_xor(val, o);
    if (lane == 0) atomicAdd(&out[b], val);
}

extern "C" void kernel_launch(void* const* d_in, const int* in_sizes, int n_in,
                              void* d_out, int out_size, void* d_ws, size_t ws_size,
                              hipStream_t stream) {
    (void)in_sizes; (void)n_in;
    const float* ru    = (const float*)d_in[0];
    const float* en    = (const float*)d_in[1];
    const float* ruWih = (const float*)d_in[2];
    const float* ruWhh = (const float*)d_in[3];
    const float* rubih = (const float*)d_in[4];
    const float* rubhh = (const float*)d_in[5];
    const float* enWih = (const float*)d_in[6];
    const float* enWhh = (const float*)d_in[7];
    const float* enbih = (const float*)d_in[8];
    const float* enbhh = (const float*)d_in[9];
    const float* W1    = (const float*)d_in[10];
    const float* b1    = (const float*)d_in[11];
    const float* W2    = (const float*)d_in[12];
    const float* b2    = (const float*)d_in[13];
    float* out = (float*)d_out;

    hipMemsetAsync(d_out, 0, (size_t)out_size * sizeof(float), stream);

    const size_t xi_bytes = (size_t)ROWS_TOTAL * 30 * sizeof(float);  // ~63 MB
    if (ws_size >= xi_bytes) {
        float* xi = (float*)d_ws;
        // Phase 1: 8192 waves, 64 rows each (4 serial 16-row tiles)
        xi_gemm<<<dim3(2048), dim3(256), 0, stream>>>(
            ru, en, ruWih, rubih, enWih, enbih, xi);
        // Phase 2: 4096 chains, 2 per wave
        gru_scan<<<dim3(512), dim3(256), 0, stream>>>(
            xi, ruWhh, rubhh, enWhh, enbhh, W1, b1, W2, b2, out);
    } else {
        gru_fused<<<dim3(1024), dim3(256), 0, stream>>>(
            ru, en, ruWih, ruWhh, rubih, rubhh,
            enWih, enWhh, enbih, enbhh, W1, b1, W2, b2, out);
    }
}